// Round 1
// baseline (554.245 us; speedup 1.0000x reference)
//
#include <hip/hip_runtime.h>
#include <hip/hip_bf16.h>

#define Bb 2
#define Ss 4096
#define Dd 512
#define Hh 8
#define DHh 64

typedef __attribute__((ext_vector_type(8))) short short8;
typedef __attribute__((ext_vector_type(4))) float floatx4;

static __device__ __forceinline__ ushort bfbits(float f) {
  union { __hip_bfloat16 h; ushort u; } cv;
  cv.h = __float2bfloat16(f);
  return cv.u;
}

// ---------------- fp32 -> bf16 conversion (vector x4) ----------------
__global__ void cvt_bf16_4(const float* __restrict__ in, ushort* __restrict__ out, int n4) {
  int i = blockIdx.x * blockDim.x + threadIdx.x;
  if (i >= n4) return;
  float4 f = ((const float4*)in)[i];
  ushort4 u;
  u.x = bfbits(f.x); u.y = bfbits(f.y); u.z = bfbits(f.z); u.w = bfbits(f.w);
  ((ushort4*)out)[i] = u;
}

// ---------------- NT GEMM: Y = A @ B^T + bias ----------------
// A [M,K] bf16 row-major, Bw [N,K] bf16 row-major (torch Linear weight).
// MODE 0: store bf16 head-swizzled to [B,H,S,DH]  (for q/k/v)
// MODE 1: store fp32 row-major [M,N]              (final output)
template<int MODE>
__global__ __launch_bounds__(256) void gemm_nt(
    const ushort* __restrict__ A, const ushort* __restrict__ Bw,
    const float* __restrict__ bias, void* __restrict__ outp,
    int M, int N, int K)
{
  int nblk = N >> 6;
  int mb = blockIdx.x / nblk, nb = blockIdx.x % nblk;
  int lane = threadIdx.x & 63, w = threadIdx.x >> 6;
  int g = lane >> 4, ln = lane & 15;
  int m0 = mb * 64 + w * 16;                       // wave's 16 rows
  const ushort* ap = A + (size_t)(m0 + ln) * K + g * 8;
  const ushort* bp = Bw + (size_t)(nb * 64 + ln) * K + g * 8;
  floatx4 acc[4] = {};
  for (int k0 = 0; k0 < K; k0 += 32) {
    short8 af = *(const short8*)(ap + k0);
#pragma unroll
    for (int ns = 0; ns < 4; ++ns) {
      short8 bf = *(const short8*)(bp + (size_t)ns * 16 * K + k0);
      acc[ns] = __builtin_amdgcn_mfma_f32_16x16x32_bf16(af, bf, acc[ns], 0, 0, 0);
    }
  }
#pragma unroll
  for (int ns = 0; ns < 4; ++ns) {
    int col = nb * 64 + ns * 16 + ln;
    float bv = bias[col];
#pragma unroll
    for (int r = 0; r < 4; ++r) {
      int i = m0 + g * 4 + r;
      float vv = acc[ns][r] + bv;
      if (MODE == 0) {
        int bI = i >> 12, s = i & (Ss - 1);        // S = 4096 = 2^12
        int hh = col >> 6, dh = col & (DHh - 1);   // DH = 64
        ((ushort*)outp)[(((size_t)bI * Hh + hh) * Ss + s) * DHh + dh] = bfbits(vv);
      } else {
        ((float*)outp)[(size_t)i * N + col] = vv;
      }
    }
  }
}

// ---------------- flash attention with causal mask + hyperbolic bias ----------------
// q,k,v: [B,H,S,DH] bf16.  gamma: [B,S] fp32.  o: [B,S,H*DH] bf16.
// block = 256 threads = 4 waves; block handles (b,h,64 queries); wave handles 16 queries.
__global__ __launch_bounds__(256) void flash_kernel(
    const ushort* __restrict__ q, const ushort* __restrict__ k,
    const ushort* __restrict__ v, const float* __restrict__ gamma,
    ushort* __restrict__ o)
{
  __shared__ __align__(16) ushort Kt[64 * 72];      // [key][d], pad 72 keeps 16B align
  __shared__ __align__(16) ushort Vt[64 * 72];      // [dh][key] transposed
  __shared__ __align__(16) ushort Pb[4][16 * 72];   // per-wave P transpose buffer

  int nqt = Ss / 64;
  int qt = blockIdx.x % nqt;
  int bh = blockIdx.x / nqt;          // b*H + h
  int hh = bh & (Hh - 1);
  int b  = bh >> 3;
  int tid = threadIdx.x;
  int lane = tid & 63, w = tid >> 6;
  int g = lane >> 4, ln = lane & 15;
  int q0 = qt * 64 + w * 16;          // wave's query base

  // Q fragments (A-operand layout: row=lane&15, k=quad*8+j)
  const ushort* qp = q + ((size_t)bh * Ss + q0 + ln) * DHh + g * 8;
  short8 qf0 = *(const short8*)qp;          // d 0..31
  short8 qf1 = *(const short8*)(qp + 32);   // d 32..63

  float m_r[4], l_r[4], gm[4];
  floatx4 oacc[4] = {};
#pragma unroll
  for (int r = 0; r < 4; ++r) {
    m_r[r] = -1e30f; l_r[r] = 0.0f;
    gm[r] = gamma[(size_t)b * Ss + q0 + g * 4 + r];
  }

  const ushort* kp = k + (size_t)bh * Ss * DHh;
  const ushort* vp = v + (size_t)bh * Ss * DHh;

  for (int kt = 0; kt <= qt; ++kt) {
    int kbase = kt * 64;
    __syncthreads();                   // protect previous tile's LDS reads
    // cooperative stage: K straight, V transposed
    for (int c = tid; c < 512; c += 256) {
      int key = c >> 3, dc = (c & 7) * 8;
      *(short8*)(&Kt[key * 72 + dc]) =
          *(const short8*)(kp + (size_t)(kbase + key) * DHh + dc);
      int vkey = c & 63, vdc = (c >> 6) * 8;
      short8 vv = *(const short8*)(vp + (size_t)(kbase + vkey) * DHh + vdc);
      ushort* vq = (ushort*)&vv;
#pragma unroll
      for (int j = 0; j < 8; ++j) Vt[(vdc + j) * 72 + vkey] = vq[j];
    }
    __syncthreads();

    // scores: 16 queries x 64 keys via 8 MFMAs
    floatx4 sacc[4];
#pragma unroll
    for (int ns = 0; ns < 4; ++ns) {
      short8 b0 = *(const short8*)(&Kt[(ns * 16 + ln) * 72 + g * 8]);
      short8 b1 = *(const short8*)(&Kt[(ns * 16 + ln) * 72 + 32 + g * 8]);
      floatx4 z = {};
      z = __builtin_amdgcn_mfma_f32_16x16x32_bf16(qf0, b0, z, 0, 0, 0);
      z = __builtin_amdgcn_mfma_f32_16x16x32_bf16(qf1, b1, z, 0, 0, 0);
      sacc[ns] = z;
    }

    // scale + hyperbolic bias + causal mask (C-layout: col=ln, row=g*4+r)
    bool diag = (kt == qt);
    float s_v[4][4];
#pragma unroll
    for (int ns = 0; ns < 4; ++ns) {
      int j = kbase + ns * 16 + ln;
#pragma unroll
      for (int r = 0; r < 4; ++r) {
        int i = q0 + g * 4 + r;
        if (diag && j > i) {
          s_v[ns][r] = -1e30f;
        } else {
          float delta = (float)(i - j);
          s_v[ns][r] = sacc[ns][r] * 0.125f - __logf(fmaf(gm[r], delta, 1.0f + 1e-8f));
        }
      }
    }

    // online softmax: row reduce across 16 lanes of the group
    float al[4];
    ushort pb16[4][4];
#pragma unroll
    for (int r = 0; r < 4; ++r) {
      float mx = fmaxf(fmaxf(s_v[0][r], s_v[1][r]), fmaxf(s_v[2][r], s_v[3][r]));
      mx = fmaxf(mx, __shfl_xor(mx, 1));
      mx = fmaxf(mx, __shfl_xor(mx, 2));
      mx = fmaxf(mx, __shfl_xor(mx, 4));
      mx = fmaxf(mx, __shfl_xor(mx, 8));
      float mn = fmaxf(m_r[r], mx);
      al[r] = __expf(m_r[r] - mn);
      m_r[r] = mn;
      float rs = 0.0f;
#pragma unroll
      for (int ns = 0; ns < 4; ++ns) {
        float p = __expf(s_v[ns][r] - mn);
        rs += p;
        pb16[ns][r] = bfbits(p);
      }
      rs += __shfl_xor(rs, 1);
      rs += __shfl_xor(rs, 2);
      rs += __shfl_xor(rs, 4);
      rs += __shfl_xor(rs, 8);
      l_r[r] = l_r[r] * al[r] + rs;
    }

    // rescale O accumulators
#pragma unroll
    for (int ds = 0; ds < 4; ++ds)
#pragma unroll
      for (int r = 0; r < 4; ++r) oacc[ds][r] *= al[r];

    // P: C-layout -> A-layout via wave-private LDS (in-order per-wave DS ops)
    ushort* pw = &Pb[w][0];
#pragma unroll
    for (int ns = 0; ns < 4; ++ns)
#pragma unroll
      for (int r = 0; r < 4; ++r)
        pw[(g * 4 + r) * 72 + ns * 16 + ln] = pb16[ns][r];

    // PV: O[16q x 64dh] += P[16q x 64key] @ V[64key x 64dh]
#pragma unroll
    for (int c = 0; c < 2; ++c) {
      short8 af = *(const short8*)(&pw[ln * 72 + c * 32 + g * 8]);
#pragma unroll
      for (int ds = 0; ds < 4; ++ds) {
        short8 bf = *(const short8*)(&Vt[(ds * 16 + ln) * 72 + c * 32 + g * 8]);
        oacc[ds] = __builtin_amdgcn_mfma_f32_16x16x32_bf16(af, bf, oacc[ds], 0, 0, 0);
      }
    }
  }

  // epilogue: O /= l, store bf16 to [B,S,H*DH]
  float inv[4];
#pragma unroll
  for (int r = 0; r < 4; ++r) inv[r] = 1.0f / l_r[r];
#pragma unroll
  for (int ds = 0; ds < 4; ++ds)
#pragma unroll
    for (int r = 0; r < 4; ++r) {
      int i = q0 + g * 4 + r;
      o[((size_t)b * Ss + i) * Dd + hh * DHh + ds * 16 + ln] = bfbits(oacc[ds][r] * inv[r]);
    }
}

extern "C" void kernel_launch(void* const* d_in, const int* in_sizes, int n_in,
                              void* d_out, int out_size, void* d_ws, size_t ws_size,
                              hipStream_t stream) {
  const float* x     = (const float*)d_in[0];
  const float* gamma = (const float*)d_in[1];
  const float* Wq    = (const float*)d_in[2];
  const float* bq    = (const float*)d_in[3];
  const float* Wk    = (const float*)d_in[4];
  const float* bk    = (const float*)d_in[5];
  const float* Wv    = (const float*)d_in[6];
  const float* bv    = (const float*)d_in[7];
  const float* Wo    = (const float*)d_in[8];
  const float* bo    = (const float*)d_in[9];

  const size_t NX = (size_t)Bb * Ss * Dd;   // 4,194,304
  const size_t NW = (size_t)Dd * Dd;        // 262,144
  ushort* xb  = (ushort*)d_ws;              // ws usage: ~44 MB total
  ushort* Wqb = xb + NX;
  ushort* Wkb = Wqb + NW;
  ushort* Wvb = Wkb + NW;
  ushort* Wob = Wvb + NW;
  ushort* qb  = Wob + NW;
  ushort* kb  = qb + NX;
  ushort* vb  = kb + NX;
  ushort* ab  = vb + NX;

  cvt_bf16_4<<<(int)((NX / 4 + 255) / 256), 256, 0, stream>>>(x,  xb,  (int)(NX / 4));
  cvt_bf16_4<<<(int)((NW / 4 + 255) / 256), 256, 0, stream>>>(Wq, Wqb, (int)(NW / 4));
  cvt_bf16_4<<<(int)((NW / 4 + 255) / 256), 256, 0, stream>>>(Wk, Wkb, (int)(NW / 4));
  cvt_bf16_4<<<(int)((NW / 4 + 255) / 256), 256, 0, stream>>>(Wv, Wvb, (int)(NW / 4));
  cvt_bf16_4<<<(int)((NW / 4 + 255) / 256), 256, 0, stream>>>(Wo, Wob, (int)(NW / 4));

  const int M = Bb * Ss, N = Dd, K = Dd;
  const int gblocks = (M / 64) * (N / 64);  // 1024
  gemm_nt<0><<<gblocks, 256, 0, stream>>>(xb, Wqb, bq, qb, M, N, K);
  gemm_nt<0><<<gblocks, 256, 0, stream>>>(xb, Wkb, bk, kb, M, N, K);
  gemm_nt<0><<<gblocks, 256, 0, stream>>>(xb, Wvb, bv, vb, M, N, K);

  flash_kernel<<<Bb * Hh * (Ss / 64), 256, 0, stream>>>(qb, kb, vb, gamma, ab);

  gemm_nt<1><<<gblocks, 256, 0, stream>>>(ab, Wob, bo, d_out, M, N, K);
}

// Round 2
// 488.241 us; speedup vs baseline: 1.1352x; 1.1352x over previous
//
#include <hip/hip_runtime.h>
#include <hip/hip_bf16.h>

#define Bb 2
#define Ss 4096
#define Dd 512
#define Hh 8
#define DHh 64

typedef __attribute__((ext_vector_type(8))) short short8;
typedef __attribute__((ext_vector_type(4))) float floatx4;

static __device__ __forceinline__ ushort bfbits(float f) {
  union { __hip_bfloat16 h; ushort u; } cv;
  cv.h = __float2bfloat16(f);
  return cv.u;
}

// ---------------- merged fp32 -> bf16: [x | Wq | Wk | Wv | Wo] ----------------
__global__ void cvt_all(const float* __restrict__ x,
                        const float* __restrict__ w0, const float* __restrict__ w1,
                        const float* __restrict__ w2, const float* __restrict__ w3,
                        ushort* __restrict__ out) {
  const int XN4 = (Bb * Ss * Dd) / 4;   // 1,048,576
  const int WN4 = (Dd * Dd) / 4;        // 65,536 = 2^16
  int i = blockIdx.x * blockDim.x + threadIdx.x;
  if (i >= XN4 + 4 * WN4) return;
  const float* s; int li;
  if (i < XN4) { s = x; li = i; }
  else {
    int t = i - XN4; int j = t >> 16; li = t & (WN4 - 1);
    s = (j == 0) ? w0 : (j == 1) ? w1 : (j == 2) ? w2 : w3;
  }
  float4 f = ((const float4*)s)[li];
  ushort4 u;
  u.x = bfbits(f.x); u.y = bfbits(f.y); u.z = bfbits(f.z); u.w = bfbits(f.w);
  ((ushort4*)out)[i] = u;
}

// ---------------- NT GEMM: Y = (A @ B^T + bias) * scale ----------------
// A [M,K] bf16 row-major, Bw [N,K] bf16 row-major.
// MODE 0: bf16 head-swizzled [B,H,S,DH]      (q, k)
// MODE 1: fp32 row-major [M,N]               (final out)
// MODE 2: bf16 transposed  [B,H,DH,S]        (V^T for flash)
template<int MODE>
__global__ __launch_bounds__(256) void gemm_nt(
    const ushort* __restrict__ A, const ushort* __restrict__ Bw,
    const float* __restrict__ bias, void* __restrict__ outp,
    int M, int N, int K, float scale)
{
  int nblk = N >> 6;
  int mb = blockIdx.x / nblk, nb = blockIdx.x % nblk;
  int lane = threadIdx.x & 63, w = threadIdx.x >> 6;
  int g = lane >> 4, ln = lane & 15;
  int m0 = mb * 64 + w * 16;
  const ushort* ap = A + (size_t)(m0 + ln) * K + g * 8;
  const ushort* bp = Bw + (size_t)(nb * 64 + ln) * K + g * 8;
  floatx4 acc[4] = {};
  for (int k0 = 0; k0 < K; k0 += 32) {
    short8 af = *(const short8*)(ap + k0);
#pragma unroll
    for (int ns = 0; ns < 4; ++ns) {
      short8 bf = *(const short8*)(bp + (size_t)ns * 16 * K + k0);
      acc[ns] = __builtin_amdgcn_mfma_f32_16x16x32_bf16(af, bf, acc[ns], 0, 0, 0);
    }
  }
#pragma unroll
  for (int ns = 0; ns < 4; ++ns) {
    int col = nb * 64 + ns * 16 + ln;
    float bv = bias[col];
    if (MODE == 2) {
      int hh = col >> 6, dh = col & (DHh - 1);
      int i0 = m0 + g * 4;
      int bI = i0 >> 12, s0 = i0 & (Ss - 1);
      ushort4 pk;
      pk.x = bfbits((acc[ns][0] + bv) * scale);
      pk.y = bfbits((acc[ns][1] + bv) * scale);
      pk.z = bfbits((acc[ns][2] + bv) * scale);
      pk.w = bfbits((acc[ns][3] + bv) * scale);
      *(ushort4*)((ushort*)outp + (((size_t)bI * Hh + hh) * DHh + dh) * Ss + s0) = pk;
    } else {
#pragma unroll
      for (int r = 0; r < 4; ++r) {
        int i = m0 + g * 4 + r;
        float vv = (acc[ns][r] + bv) * scale;
        if (MODE == 0) {
          int bI = i >> 12, s = i & (Ss - 1);
          int hh = col >> 6, dh = col & (DHh - 1);
          ((ushort*)outp)[(((size_t)bI * Hh + hh) * Ss + s) * DHh + dh] = bfbits(vv);
        } else {
          ((float*)outp)[(size_t)i * N + col] = vv;
        }
      }
    }
  }
}

// ---------------- barrier-free flash attention ----------------
// q,k: [B,H,S,DH] bf16 (q pre-scaled by 1/8). vt: [B,H,DH,S] bf16. gamma: [B,S] fp32.
// o: [B,S,H*DH] bf16.  Block = 128 threads = 2 waves; wave owns 16 queries.
// No __syncthreads: K/V^T fragments loaded directly from global (L2-hot),
// P transpose via wave-private LDS. Grid swizzled so each CU's blocks sum to
// near-constant work.
__global__ __launch_bounds__(128, 4) void flash2(
    const ushort* __restrict__ q, const ushort* __restrict__ k,
    const ushort* __restrict__ vt, const float* __restrict__ gamma,
    ushort* __restrict__ o)
{
  __shared__ __align__(16) ushort Pb[2][16 * 72];
  int idx = blockIdx.x;
  int a = idx & 255, sg = idx >> 8;                 // sg 0..7
  int bh = a & 15, u = a >> 4;                      // u 0..15
  int q32 = sg * 16 + ((sg & 1) ? (15 - u) : u);    // balanced 32-query tile id
  int b = bh >> 3, hh = bh & 7;
  int tid = threadIdx.x;
  int wv = tid >> 6, lane = tid & 63;
  int g = lane >> 4, ln = lane & 15;
  int q0 = q32 * 32 + wv * 16;
  int ktm = q32 >> 1;                               // last 64-key tile
  ushort* pw = &Pb[wv][0];

  const ushort* qp = q + ((size_t)bh * Ss + q0 + ln) * DHh + g * 8;
  short8 qf0 = *(const short8*)qp;
  short8 qf1 = *(const short8*)(qp + 32);

  const ushort* kp = k + (size_t)bh * Ss * DHh + (size_t)ln * DHh + g * 8;
  const ushort* vp = vt + (size_t)bh * DHh * Ss + (size_t)ln * Ss + g * 8;

  float m_r[4], l_r[4], gm[4];
  floatx4 oacc[4] = {};
#pragma unroll
  for (int r = 0; r < 4; ++r) {
    m_r[r] = -1e30f; l_r[r] = 0.0f;
    gm[r] = gamma[(size_t)b * Ss + q0 + g * 4 + r];
  }
  int ibase = q0 + g * 4 - ln;   // (i - j) = ibase + r - kbase - 16*ns

  for (int kt = 0; kt <= ktm; ++kt) {
    int kbase = kt * 64;
    // scores (q pre-scaled by 1/8)
    const ushort* kb_ = kp + (size_t)kbase * DHh;
    float sv[4][4];
#pragma unroll
    for (int ns = 0; ns < 4; ++ns) {
      short8 b0 = *(const short8*)(kb_ + (size_t)(ns * 16) * DHh);
      short8 b1 = *(const short8*)(kb_ + (size_t)(ns * 16) * DHh + 32);
      floatx4 z = {};
      z = __builtin_amdgcn_mfma_f32_16x16x32_bf16(qf0, b0, z, 0, 0, 0);
      z = __builtin_amdgcn_mfma_f32_16x16x32_bf16(qf1, b1, z, 0, 0, 0);
#pragma unroll
      for (int r = 0; r < 4; ++r) sv[ns][r] = z[r];
    }
    // issue V^T fragment loads early; softmax VALU hides their latency
    short8 vf[8];
    const ushort* vb_ = vp + kbase;
#pragma unroll
    for (int cc = 0; cc < 8; ++cc) {
      int ds = cc & 3, c = cc >> 2;
      vf[cc] = *(const short8*)(vb_ + (size_t)(ds * 16) * Ss + c * 32);
    }
    // causal mask: only the last tile can contain j > i
    if (kt == ktm) {
#pragma unroll
      for (int ns = 0; ns < 4; ++ns) {
        int jd = ibase - kbase - 16 * ns;
#pragma unroll
        for (int r = 0; r < 4; ++r)
          if (jd + r < 0) sv[ns][r] = -1e30f;
      }
    }
    // online max over raw scores (bias weight is multiplicative, <= 1)
    float mn[4], al[4];
#pragma unroll
    for (int r = 0; r < 4; ++r) {
      float mx = fmaxf(fmaxf(sv[0][r], sv[1][r]), fmaxf(sv[2][r], sv[3][r]));
      mx = fmaxf(mx, __shfl_xor(mx, 1));
      mx = fmaxf(mx, __shfl_xor(mx, 2));
      mx = fmaxf(mx, __shfl_xor(mx, 4));
      mx = fmaxf(mx, __shfl_xor(mx, 8));
      mn[r] = fmaxf(m_r[r], mx);
      al[r] = __expf(m_r[r] - mn[r]);
      m_r[r] = mn[r];
    }
    // p = exp(s - m) / (1 + gm * max(i-j, 0))   [== exp(s - log1p(gm*delta) - m)]
    float fd = (float)(ibase - kbase);
#pragma unroll
    for (int ns = 0; ns < 4; ++ns) {
#pragma unroll
      for (int r = 0; r < 4; ++r) {
        float delta = fmaxf(fd + (float)(r - 16 * ns), 0.0f);
        float w = __builtin_amdgcn_rcpf(fmaf(gm[r], delta, 1.0f));
        sv[ns][r] = __expf(sv[ns][r] - mn[r]) * w;
      }
    }
    // deferred-l: per-lane partial sums only; reduce across lanes in epilogue
#pragma unroll
    for (int r = 0; r < 4; ++r) {
      float rs = (sv[0][r] + sv[1][r]) + (sv[2][r] + sv[3][r]);
      l_r[r] = l_r[r] * al[r] + rs;
#pragma unroll
      for (int ds = 0; ds < 4; ++ds) oacc[ds][r] *= al[r];
    }
    // P: C-layout -> A-layout via wave-private LDS (in-order DS pipe, no barrier)
#pragma unroll
    for (int ns = 0; ns < 4; ++ns)
#pragma unroll
      for (int r = 0; r < 4; ++r)
        pw[(g * 4 + r) * 72 + ns * 16 + ln] = bfbits(sv[ns][r]);
#pragma unroll
    for (int c = 0; c < 2; ++c) {
      short8 af = *(const short8*)(&pw[ln * 72 + c * 32 + g * 8]);
#pragma unroll
      for (int ds = 0; ds < 4; ++ds)
        oacc[ds] = __builtin_amdgcn_mfma_f32_16x16x32_bf16(af, vf[c * 4 + ds], oacc[ds], 0, 0, 0);
    }
  }

  // epilogue: reduce l across the 16 lanes of each row, normalize, store
#pragma unroll
  for (int r = 0; r < 4; ++r) {
    float l = l_r[r];
    l += __shfl_xor(l, 1);
    l += __shfl_xor(l, 2);
    l += __shfl_xor(l, 4);
    l += __shfl_xor(l, 8);
    l_r[r] = 1.0f / l;
  }
#pragma unroll
  for (int ds = 0; ds < 4; ++ds)
#pragma unroll
    for (int r = 0; r < 4; ++r) {
      int i = q0 + g * 4 + r;
      o[((size_t)b * Ss + i) * Dd + hh * DHh + ds * 16 + ln] = bfbits(oacc[ds][r] * l_r[r]);
    }
}

extern "C" void kernel_launch(void* const* d_in, const int* in_sizes, int n_in,
                              void* d_out, int out_size, void* d_ws, size_t ws_size,
                              hipStream_t stream) {
  const float* x     = (const float*)d_in[0];
  const float* gamma = (const float*)d_in[1];
  const float* Wq    = (const float*)d_in[2];
  const float* bq    = (const float*)d_in[3];
  const float* Wk    = (const float*)d_in[4];
  const float* bk    = (const float*)d_in[5];
  const float* Wv    = (const float*)d_in[6];
  const float* bv    = (const float*)d_in[7];
  const float* Wo    = (const float*)d_in[8];
  const float* bo    = (const float*)d_in[9];

  const size_t NX = (size_t)Bb * Ss * Dd;   // 4,194,304
  const size_t NW = (size_t)Dd * Dd;        // 262,144
  ushort* xb  = (ushort*)d_ws;
  ushort* Wqb = xb + NX;
  ushort* Wkb = Wqb + NW;
  ushort* Wvb = Wkb + NW;
  ushort* Wob = Wvb + NW;
  ushort* qb  = Wob + NW;
  ushort* kb  = qb + NX;
  ushort* vtb = kb + NX;
  ushort* ab  = vtb + NX;

  const int total4 = (int)(NX / 4 + 4 * (NW / 4));
  cvt_all<<<(total4 + 255) / 256, 256, 0, stream>>>(x, Wq, Wk, Wv, Wo, xb);

  const int M = Bb * Ss, N = Dd, K = Dd;
  const int gblocks = (M / 64) * (N / 64);  // 1024
  gemm_nt<0><<<gblocks, 256, 0, stream>>>(xb, Wqb, bq, qb,  M, N, K, 0.125f);
  gemm_nt<0><<<gblocks, 256, 0, stream>>>(xb, Wkb, bk, kb,  M, N, K, 1.0f);
  gemm_nt<2><<<gblocks, 256, 0, stream>>>(xb, Wvb, bv, vtb, M, N, K, 1.0f);

  flash2<<<2048, 128, 0, stream>>>(qb, kb, vtb, gamma, ab);

  gemm_nt<1><<<gblocks, 256, 0, stream>>>(ab, Wob, bo, d_out, M, N, K, 1.0f);
}

// Round 3
// 368.774 us; speedup vs baseline: 1.5029x; 1.3240x over previous
//
#include <hip/hip_runtime.h>
#include <hip/hip_bf16.h>

#define Bb 2
#define Ss 4096
#define Dd 512
#define Hh 8
#define DHh 64

typedef __attribute__((ext_vector_type(8))) short short8;
typedef __attribute__((ext_vector_type(4))) float floatx4;

static __device__ __forceinline__ ushort bfbits(float f) {
  union { __hip_bfloat16 h; ushort u; } cv;
  cv.h = __float2bfloat16(f);
  return cv.u;
}

// ---------------- merged fp32 -> bf16: [x | Wq | Wk | Wv | Wo] ----------------
__global__ void cvt_all(const float* __restrict__ x,
                        const float* __restrict__ w0, const float* __restrict__ w1,
                        const float* __restrict__ w2, const float* __restrict__ w3,
                        ushort* __restrict__ out) {
  const int XN4 = (Bb * Ss * Dd) / 4;
  const int WN4 = (Dd * Dd) / 4;        // 65,536 = 2^16
  int i = blockIdx.x * blockDim.x + threadIdx.x;
  if (i >= XN4 + 4 * WN4) return;
  const float* s; int li;
  if (i < XN4) { s = x; li = i; }
  else {
    int t = i - XN4; int j = t >> 16; li = t & (WN4 - 1);
    s = (j == 0) ? w0 : (j == 1) ? w1 : (j == 2) ? w2 : w3;
  }
  float4 f = ((const float4*)s)[i < XN4 ? i : li];
  ushort4 u;
  u.x = bfbits(f.x); u.y = bfbits(f.y); u.z = bfbits(f.z); u.w = bfbits(f.w);
  ((ushort4*)out)[i] = u;
}

// permuted V^T position: key s (0..4095) -> within-64 slot permutation so that
// flash PV A-frags are single contiguous 16B loads.
// s = 64a + 16*kb + 4*gq + r  ->  pos = 64a + 32*(kb>>1) + 8*gq + 4*(kb&1) + r
static __device__ __forceinline__ int vperm(int s0) {  // s0 multiple of 4 (r=0)
  int kb = (s0 >> 4) & 3, gq = (s0 >> 2) & 3;
  return (s0 & ~63) | ((kb >> 1) << 5) | (gq << 3) | ((kb & 1) << 2);
}

#define LOADIT(buf, k0)                                                        \
  af[buf][0] = *(const short8*)(ap + (k0));                                    \
  af[buf][1] = *(const short8*)(ap + (k0) + 32);                               \
  _Pragma("unroll")                                                            \
  for (int ns = 0; ns < 4; ++ns) {                                             \
    bfr[buf][ns][0] = *(const short8*)(bp + (size_t)ns * 16 * 512 + (k0));     \
    bfr[buf][ns][1] = *(const short8*)(bp + (size_t)ns * 16 * 512 + (k0) + 32);\
  }

// ---------------- fused QKV projection GEMM ----------------
// xb [M,512] bf16; Wq/Wk/Wv [512,512] bf16 (row = out-feature).
// which 0 -> q [B,H,S,DH] scaled 1/8; 1 -> k [B,H,S,DH]; 2 -> v permuted-V^T [B,H,DH,S'].
__global__ __launch_bounds__(256, 4) void qkv_gemm(
    const ushort* __restrict__ xb,
    const ushort* __restrict__ Wq, const ushort* __restrict__ Wk, const ushort* __restrict__ Wv,
    const float* __restrict__ bq, const float* __restrict__ bk, const float* __restrict__ bv,
    ushort* __restrict__ qo, ushort* __restrict__ ko, ushort* __restrict__ vo)
{
  int mb = blockIdx.x / 24, nbt = blockIdx.x % 24;
  int which = nbt >> 3, nb = nbt & 7;
  const ushort* Bw  = (which == 0) ? Wq : (which == 1) ? Wk : Wv;
  const float* bias = (which == 0) ? bq : (which == 1) ? bk : bv;
  int lane = threadIdx.x & 63, w = threadIdx.x >> 6;
  int g = lane >> 4, ln = lane & 15;
  int m0 = mb * 64 + w * 16;
  const ushort* ap = xb + (size_t)(m0 + ln) * 512 + g * 8;
  const ushort* bp = Bw + (size_t)(nb * 64 + ln) * 512 + g * 8;
  floatx4 acc[4] = {};
  short8 af[2][2], bfr[2][4][2];
  LOADIT(0, 0)
#pragma unroll
  for (int it = 0; it < 8; ++it) {
    int cur = it & 1;
    if (it < 7) { LOADIT(cur ^ 1, (it + 1) * 64) }
#pragma unroll
    for (int ns = 0; ns < 4; ++ns) {
      acc[ns] = __builtin_amdgcn_mfma_f32_16x16x32_bf16(af[cur][0], bfr[cur][ns][0], acc[ns], 0, 0, 0);
      acc[ns] = __builtin_amdgcn_mfma_f32_16x16x32_bf16(af[cur][1], bfr[cur][ns][1], acc[ns], 0, 0, 0);
    }
  }
  float scale = (which == 0) ? 0.125f : 1.0f;
#pragma unroll
  for (int ns = 0; ns < 4; ++ns) {
    int col = nb * 64 + ns * 16 + ln;
    float bv_ = bias[col];
    int hh = col >> 6, dh = col & 63;
    if (which == 2) {
      int i0 = m0 + g * 4;
      int bI = i0 >> 12, s0 = i0 & (Ss - 1);
      ushort4 pk;
      pk.x = bfbits(acc[ns][0] + bv_);
      pk.y = bfbits(acc[ns][1] + bv_);
      pk.z = bfbits(acc[ns][2] + bv_);
      pk.w = bfbits(acc[ns][3] + bv_);
      *(ushort4*)(vo + (((size_t)bI * Hh + hh) * DHh + dh) * Ss + vperm(s0)) = pk;
    } else {
      ushort* outp = (which == 0) ? qo : ko;
#pragma unroll
      for (int r = 0; r < 4; ++r) {
        int i = m0 + g * 4 + r;
        int bI = i >> 12, s = i & (Ss - 1);
        outp[(((size_t)bI * Hh + hh) * Ss + s) * DHh + dh] = bfbits((acc[ns][r] + bv_) * scale);
      }
    }
  }
}

// ---------------- output projection GEMM (fp32 out) ----------------
__global__ __launch_bounds__(256, 4) void gemm_out(
    const ushort* __restrict__ A, const ushort* __restrict__ Bw,
    const float* __restrict__ bias, float* __restrict__ outp)
{
  int mb = blockIdx.x >> 3, nb = blockIdx.x & 7;
  int lane = threadIdx.x & 63, w = threadIdx.x >> 6;
  int g = lane >> 4, ln = lane & 15;
  int m0 = mb * 64 + w * 16;
  const ushort* ap = A + (size_t)(m0 + ln) * 512 + g * 8;
  const ushort* bp = Bw + (size_t)(nb * 64 + ln) * 512 + g * 8;
  floatx4 acc[4] = {};
  short8 af[2][2], bfr[2][4][2];
  LOADIT(0, 0)
#pragma unroll
  for (int it = 0; it < 8; ++it) {
    int cur = it & 1;
    if (it < 7) { LOADIT(cur ^ 1, (it + 1) * 64) }
#pragma unroll
    for (int ns = 0; ns < 4; ++ns) {
      acc[ns] = __builtin_amdgcn_mfma_f32_16x16x32_bf16(af[cur][0], bfr[cur][ns][0], acc[ns], 0, 0, 0);
      acc[ns] = __builtin_amdgcn_mfma_f32_16x16x32_bf16(af[cur][1], bfr[cur][ns][1], acc[ns], 0, 0, 0);
    }
  }
#pragma unroll
  for (int ns = 0; ns < 4; ++ns) {
    int col = nb * 64 + ns * 16 + ln;
    float bv_ = bias[col];
#pragma unroll
    for (int r = 0; r < 4; ++r)
      outp[(size_t)(m0 + g * 4 + r) * 512 + col] = acc[ns][r] + bv_;
  }
}

// ---------------- flash attention, S^T formulation, zero-LDS main loop ----------------
// q,k: [B,H,S,DH] bf16 (q pre-scaled 1/8). vt: permuted V^T. gamma: [B,S] fp32.
// o: [B,S,512] bf16.  Block = 128 thr = 2 waves; wave owns 32 queries (2 MFMA row-blocks).
// Wave pairing (t, 127-t) -> every block exactly 65 key-tiles; grid 1024 all-resident.
__global__ __launch_bounds__(128, 2) void flash3(
    const ushort* __restrict__ q, const ushort* __restrict__ k,
    const ushort* __restrict__ vt, const float* __restrict__ gamma,
    ushort* __restrict__ o)
{
  __shared__ __align__(16) ushort Tb[2][16 * 72];
  int z = blockIdx.x;
  int bh = z & 15, p = z >> 4;
  int wv = threadIdx.x >> 6, lane = threadIdx.x & 63;
  int t = wv ? (127 - p) : p;           // 32-query tile id, 0..127
  int b = bh >> 3, hh = bh & 7;
  int g = lane >> 4, ln = lane & 15;
  int q0 = t * 32;
  int ktm = t >> 1;

  // Q fragments for both 16-row blocks (B-operand layout)
  const ushort* qp = q + ((size_t)bh * Ss + q0 + ln) * DHh + g * 8;
  short8 qf00 = *(const short8*)qp;
  short8 qf01 = *(const short8*)(qp + 32);
  short8 qf10 = *(const short8*)(qp + 16 * DHh);
  short8 qf11 = *(const short8*)(qp + 16 * DHh + 32);

  const ushort* kp = k + ((size_t)bh * Ss + ln) * DHh + g * 8;
  const ushort* vp = vt + ((size_t)bh * DHh + ln) * Ss + g * 8;

  int qrow0 = q0 + ln, qrow1 = q0 + 16 + ln;
  float gm0 = gamma[(size_t)b * Ss + qrow0];
  float gm1 = gamma[(size_t)b * Ss + qrow1];
  float m2[2] = {-1e30f, -1e30f}, l2[2] = {0.0f, 0.0f};
  floatx4 oacc[2][4] = {};

  short8 kfl[4], kfh[4], vf[8];
  // initial loads (kt = 0)
#pragma unroll
  for (int ns = 0; ns < 4; ++ns) {
    kfl[ns] = *(const short8*)(kp + (size_t)(ns * 16) * DHh);
    kfh[ns] = *(const short8*)(kp + (size_t)(ns * 16) * DHh + 32);
  }
#pragma unroll
  for (int cc = 0; cc < 8; ++cc)
    vf[cc] = *(const short8*)(vp + (size_t)((cc & 3) * 16) * Ss + (cc >> 2) * 32);

  for (int kt = 0; kt <= ktm; ++kt) {
    int kbase = kt * 64;
    // ---- S^T = K . Q^T : 16 MFMAs ----
    float sv[2][16];
#pragma unroll
    for (int ns = 0; ns < 4; ++ns) {
      floatx4 z0 = {}, z1 = {};
      z0 = __builtin_amdgcn_mfma_f32_16x16x32_bf16(kfl[ns], qf00, z0, 0, 0, 0);
      z0 = __builtin_amdgcn_mfma_f32_16x16x32_bf16(kfh[ns], qf01, z0, 0, 0, 0);
      z1 = __builtin_amdgcn_mfma_f32_16x16x32_bf16(kfl[ns], qf10, z1, 0, 0, 0);
      z1 = __builtin_amdgcn_mfma_f32_16x16x32_bf16(kfh[ns], qf11, z1, 0, 0, 0);
#pragma unroll
      for (int r = 0; r < 4; ++r) { sv[0][ns * 4 + r] = z0[r]; sv[1][ns * 4 + r] = z1[r]; }
    }
    // ---- prefetch next K tile (lead = softmax + PV) ----
    if (kt < ktm) {
      const ushort* kn = kp + (size_t)(kbase + 64) * DHh;
#pragma unroll
      for (int ns = 0; ns < 4; ++ns) {
        kfl[ns] = *(const short8*)(kn + (size_t)(ns * 16) * DHh);
        kfh[ns] = *(const short8*)(kn + (size_t)(ns * 16) * DHh + 32);
      }
    }
    // ---- softmax (each lane owns one query per qb) ----
    bool last = (kt == ktm);
    short8 pfrag[2][2];
#pragma unroll
    for (int qb = 0; qb < 2; ++qb) {
      int qrow = qb ? qrow1 : qrow0;
      float gm = qb ? gm1 : gm0;
      int db = qrow - kbase - g * 4;     // delta = db - ns*16 - r
      if (last) {
#pragma unroll
        for (int e = 0; e < 16; ++e)
          if (db - (e >> 2) * 16 - (e & 3) < 0) sv[qb][e] = -1e30f;
      }
      float mx = sv[qb][0];
#pragma unroll
      for (int e = 1; e < 16; ++e) mx = fmaxf(mx, sv[qb][e]);
      mx = fmaxf(mx, __shfl_xor(mx, 16));
      mx = fmaxf(mx, __shfl_xor(mx, 32));
      float mn = fmaxf(m2[qb], mx);
      float al = __expf(m2[qb] - mn);
      m2[qb] = mn;
      float rs = 0.0f;
#pragma unroll
      for (int e = 0; e < 16; ++e) {
        float delta = fmaxf((float)(db - (e >> 2) * 16 - (e & 3)), 0.0f);
        float wt = __builtin_amdgcn_rcpf(fmaf(gm, delta, 1.0f));
        float pv = __expf(sv[qb][e] - mn) * wt;
        rs += pv;
        sv[qb][e] = pv;
      }
      l2[qb] = l2[qb] * al + rs;
#pragma unroll
      for (int ds = 0; ds < 4; ++ds)
#pragma unroll
        for (int r = 0; r < 4; ++r) oacc[qb][ds][r] *= al;
      // pack P^T B-frags: super-step c covers key-blocks (2c, 2c+1)
#pragma unroll
      for (int c = 0; c < 2; ++c) {
        short8 pk;
#pragma unroll
        for (int j = 0; j < 4; ++j) {
          ((ushort*)&pk)[j]     = bfbits(sv[qb][(2 * c) * 4 + j]);
          ((ushort*)&pk)[j + 4] = bfbits(sv[qb][(2 * c + 1) * 4 + j]);
        }
        pfrag[qb][c] = pk;
      }
    }
    // ---- PV: O^T += V^T . P^T : 16 MFMAs ----
#pragma unroll
    for (int c = 0; c < 2; ++c)
#pragma unroll
      for (int ds = 0; ds < 4; ++ds) {
        oacc[0][ds] = __builtin_amdgcn_mfma_f32_16x16x32_bf16(vf[c * 4 + ds], pfrag[0][c], oacc[0][ds], 0, 0, 0);
        oacc[1][ds] = __builtin_amdgcn_mfma_f32_16x16x32_bf16(vf[c * 4 + ds], pfrag[1][c], oacc[1][ds], 0, 0, 0);
      }
    // ---- prefetch next V tile (lead = next S^T + softmax) ----
    if (kt < ktm) {
      const ushort* vn = vp + kbase + 64;
#pragma unroll
      for (int cc = 0; cc < 8; ++cc)
        vf[cc] = *(const short8*)(vn + (size_t)((cc & 3) * 16) * Ss + (cc >> 2) * 32);
    }
  }

  // ---- epilogue: normalize, transpose O^T->O via per-wave LDS, store ----
#pragma unroll
  for (int qb = 0; qb < 2; ++qb) {
    float l = l2[qb];
    l += __shfl_xor(l, 16);
    l += __shfl_xor(l, 32);
    float linv = 1.0f / l;
    ushort* tb = &Tb[wv][0];
#pragma unroll
    for (int ds = 0; ds < 4; ++ds)
#pragma unroll
      for (int r = 0; r < 4; ++r)
        tb[ln * 72 + ds * 16 + g * 4 + r] = bfbits(oacc[qb][ds][r] * linv);
    short8 v0 = *(const short8*)(tb + ln * 72 + g * 16);
    short8 v1 = *(const short8*)(tb + ln * 72 + g * 16 + 8);
    size_t oa = ((size_t)b * Ss + q0 + qb * 16 + ln) * Dd + hh * DHh + g * 16;
    *(short8*)(o + oa) = v0;
    *(short8*)(o + oa + 8) = v1;
  }
}

extern "C" void kernel_launch(void* const* d_in, const int* in_sizes, int n_in,
                              void* d_out, int out_size, void* d_ws, size_t ws_size,
                              hipStream_t stream) {
  const float* x     = (const float*)d_in[0];
  const float* gamma = (const float*)d_in[1];
  const float* Wq    = (const float*)d_in[2];
  const float* bq    = (const float*)d_in[3];
  const float* Wk    = (const float*)d_in[4];
  const float* bk    = (const float*)d_in[5];
  const float* Wv    = (const float*)d_in[6];
  const float* bv    = (const float*)d_in[7];
  const float* Wo    = (const float*)d_in[8];
  const float* bo    = (const float*)d_in[9];

  const size_t NX = (size_t)Bb * Ss * Dd;
  const size_t NW = (size_t)Dd * Dd;
  ushort* xb  = (ushort*)d_ws;
  ushort* Wqb = xb + NX;
  ushort* Wkb = Wqb + NW;
  ushort* Wvb = Wkb + NW;
  ushort* Wob = Wvb + NW;
  ushort* qb  = Wob + NW;
  ushort* kb  = qb + NX;
  ushort* vtb = kb + NX;
  ushort* ab  = vtb + NX;

  const int total4 = (int)(NX / 4 + 4 * (NW / 4));
  cvt_all<<<(total4 + 255) / 256, 256, 0, stream>>>(x, Wq, Wk, Wv, Wo, xb);

  qkv_gemm<<<128 * 24, 256, 0, stream>>>(xb, Wqb, Wkb, Wvb, bq, bk, bv, qb, kb, vtb);

  flash3<<<1024, 128, 0, stream>>>(qb, kb, vtb, gamma, ab);

  gemm_out<<<1024, 256, 0, stream>>>(ab, Wob, bo, (float*)d_out);
}